// Round 1
// baseline (381.319 us; speedup 1.0000x reference)
//
#include <hip/hip_runtime.h>

// Depthwise causal conv: y[b,c,p,q] = sum_{r<6,s<11} w[c,r,s]*xm[b,c,p+r-5,q+s-5]
// xm = x masked to lower triangle (h>=w); output masked to p>=q.
// N=2, C=16, H=W=2048.

#define HDIM 2048
#define WDIM 2048
#define CH   16
#define RTAP 6
#define STAP 11

#define TH 64     // output tile rows per block
#define TW 128    // output tile cols per block
#define LDSW 144  // TW + 8 (left halo) + 8 (right halo, padded to x4)
#define LDSR 69   // TH + 5 (top halo)
#define NGRP 36   // LDSW/4 float4 groups per row

__global__ __launch_bounds__(256, 4)
void dwconv_causal(const float* __restrict__ x, const float* __restrict__ wgt,
                   float* __restrict__ out) {
  const int bx = blockIdx.x;       // tile col
  const int by = blockIdx.y;       // tile row
  const int plane = blockIdx.z;    // n*C + c, 0..31
  const int q0 = bx * TW;
  const int p0 = by * TH;
  const int tid = threadIdx.x;
  const size_t pb = (size_t)plane * HDIM * WDIM;
  const float* __restrict__ xp = x + pb;
  float* __restrict__ op = out + pb;

  // Tile entirely above the diagonal: output is all zeros. No reads.
  if (p0 + TH - 1 < q0) {
    const float4 z = make_float4(0.f, 0.f, 0.f, 0.f);
#pragma unroll
    for (int i = 0; i < (TH * TW / 4) / 256; ++i) {  // 8 float4 per thread
      int idx = i * 256 + tid;
      int row = idx >> 5;       // 32 float4 per output row
      int c4  = idx & 31;
      *(float4*)(op + (size_t)(p0 + row) * WDIM + q0 + 4 * c4) = z;
    }
    return;
  }

  __shared__ float lds[LDSR * LDSW];

  // ---- Stage input tile into LDS (causal mask + bounds applied here) ----
  // Logical LDS col lc corresponds to global col q0 - 8 + lc.
  for (int i = tid; i < LDSR * NGRP; i += 256) {
    int row = i / NGRP;
    int g = i - row * NGRP;
    int ih = p0 - 5 + row;
    int cb = q0 - 8 + 4 * g;     // global col of group start (16B aligned)
    float4 v = make_float4(0.f, 0.f, 0.f, 0.f);
    if (ih >= 0) {               // ih < HDIM always (p0+63 <= 2047)
      if (cb >= 0 && cb + 3 <= ih && cb + 3 < WDIM) {
        v = *(const float4*)(xp + (size_t)ih * WDIM + cb);
      } else {
        float* vv = &v.x;
#pragma unroll
        for (int e = 0; e < 4; ++e) {
          int iw = cb + e;
          if (iw >= 0 && iw < WDIM && iw <= ih) vv[e] = xp[(size_t)ih * WDIM + iw];
        }
      }
    }
    // XOR-swizzle group index by (row>>2)&1 so the compute-phase b128 reads
    // (16 tx lanes at 32B stride x 4 ty rows) hit all 32 banks.
    int gs = g ^ ((row >> 2) & 1);
    *(float4*)&lds[row * LDSW + 4 * gs] = v;
  }

  // Weights: block-uniform -> scalar loads into SGPRs.
  const float* __restrict__ wc = wgt + (plane & (CH - 1)) * (RTAP * STAP);
  float wr[RTAP * STAP];
#pragma unroll
  for (int i = 0; i < RTAP * STAP; ++i) wr[i] = wc[i];

  __syncthreads();

  // ---- Compute: 4x8 register blocking per thread ----
  const int ty = tid >> 4;          // 0..15, 4 output rows each
  const int tx = tid & 15;          // 0..15, 8 output cols each
  const int orow0 = ty * 4;         // local output row base
  const int ocol0 = tx * 8;         // local output col base

  float acc[4][8];
#pragma unroll
  for (int a = 0; a < 4; ++a)
#pragma unroll
    for (int b = 0; b < 8; ++b) acc[a][b] = 0.f;

#pragma unroll
  for (int ihl = 0; ihl < 9; ++ihl) {   // 9 LDS rows feed 4 output rows
    const int l = orow0 + ihl;          // LDS row
    const int xr = (l >> 2) & 1;        // de-swizzle bit
    float xrow[24];                     // logical LDS cols [ocol0, ocol0+24)
#pragma unroll
    for (int k = 0; k < 6; ++k) {
      int g = ((ocol0 >> 2) + k) ^ xr;
      *(float4*)&xrow[4 * k] = *(const float4*)&lds[l * LDSW + 4 * g];
    }
    const int rlo = (ihl - 5) > 0 ? (ihl - 5) : 0;
    const int rhi = ihl < 3 ? ihl : 3;
#pragma unroll
    for (int ro = 0; ro < 4; ++ro) {
      if (ro < rlo || ro > rhi) continue;   // compile-time after unroll
      const int rr = ihl - ro;              // tap row 0..5
#pragma unroll
      for (int s = 0; s < STAP; ++s) {
        const float wv = wr[rr * STAP + s];
#pragma unroll
        for (int cc = 0; cc < 8; ++cc)
          acc[ro][cc] += wv * xrow[cc + s + 3];  // idx in [3,20]
      }
    }
  }

  // ---- Store with causal output mask ----
#pragma unroll
  for (int ro = 0; ro < 4; ++ro) {
    const int p = p0 + orow0 + ro;
    const int qb = q0 + ocol0;
#pragma unroll
    for (int cc = 0; cc < 8; ++cc)
      if (qb + cc > p) acc[ro][cc] = 0.f;
    *(float4*)(op + (size_t)p * WDIM + qb) =
        make_float4(acc[ro][0], acc[ro][1], acc[ro][2], acc[ro][3]);
    *(float4*)(op + (size_t)p * WDIM + qb + 4) =
        make_float4(acc[ro][4], acc[ro][5], acc[ro][6], acc[ro][7]);
  }
}

extern "C" void kernel_launch(void* const* d_in, const int* in_sizes, int n_in,
                              void* d_out, int out_size, void* d_ws, size_t ws_size,
                              hipStream_t stream) {
  const float* x   = (const float*)d_in[0];
  const float* wgt = (const float*)d_in[1];
  float* out       = (float*)d_out;
  dim3 grid(WDIM / TW, HDIM / TH, 2 * CH);  // (16, 32, 32)
  dwconv_causal<<<grid, dim3(256), 0, stream>>>(x, wgt, out);
}

// Round 2
// 322.931 us; speedup vs baseline: 1.1808x; 1.1808x over previous
//
#include <hip/hip_runtime.h>
#include <stdint.h>

// Depthwise causal conv: y[b,c,p,q] = sum_{r<6,s<11} w[c,r,s]*xm[b,c,p+r-5,q+s-5]
// xm = x masked to lower triangle (h>=w); output masked to p>=q.
// N=2, C=16, H=W=2048.

#define HDIM 2048
#define WDIM 2048
#define CH   16
#define RTAP 6
#define STAP 11

#define TH 32     // output tile rows per block
#define TW 128    // output tile cols per block
#define LDSW 144  // floats/row: 8 left halo + 128 + 8 right (16B aligned)
#define LDSR 37   // TH + 5 top halo
#define NGRP 36   // 16B groups per row
#define NSLOT (LDSR * NGRP)  // 1332

__global__ __launch_bounds__(256, 7)
void dwconv_causal(const float* __restrict__ x, const float* __restrict__ wgt,
                   float* __restrict__ out) {
  const int bx = blockIdx.x, by = blockIdx.y, plane = blockIdx.z;
  const int q0 = bx * TW, p0 = by * TH;
  const int tid = threadIdx.x;
  const size_t pb = (size_t)plane * HDIM * WDIM;
  const float* __restrict__ xp = x + pb;
  float* __restrict__ op = out + pb;

  // Strictly-upper tile: all outputs zero, no reads, no LDS.
  if (p0 + TH - 1 < q0) {
    const float4 z = make_float4(0.f, 0.f, 0.f, 0.f);
#pragma unroll
    for (int i = 0; i < 4; ++i) {  // 32 rows x 32 float4
      int idx = i * 256 + tid;
      int row = idx >> 5, c4 = idx & 31;
      *(float4*)(op + (size_t)(p0 + row) * WDIM + q0 + 4 * c4) = z;
    }
    return;
  }

  __shared__ float lds[NSLOT * 4];  // 1332 x 16B = 21312 B -> 7 blocks/CU

  // Weights are block-uniform -> scalar loads (SGPRs). Issue early.
  const float* __restrict__ wc = wgt + (plane & (CH - 1)) * (RTAP * STAP);
  float wr[RTAP * STAP];
#pragma unroll
  for (int i = 0; i < RTAP * STAP; ++i) wr[i] = wc[i];

  // Physical slot s holds row = s/36, logical group g = (s%36) ^ ((row>>1)&1).
  // The XOR keeps the compute-phase ds_read_b128 at uniform 8 accesses/bank.
  // Pure tile: every staged element is in-bounds and causally valid
  // (max col q0+135 <= min row p0-5, left halo q0-8 >= 0).
  const bool pure = (bx >= 1) && (q0 + 140 <= p0);

  if (pure) {
    // Async global->LDS: no VGPR roundtrip; swizzle folded into the SOURCE
    // address (LDS dest must stay linear: wave-uniform base + lane*16).
#pragma unroll
    for (int j = 0; j < 6; ++j) {
      int slot = j * 256 + tid;
      if (slot < NSLOT) {
        int row = slot / NGRP;
        int gp = slot - row * NGRP;
        int g = gp ^ ((row >> 1) & 1);
        const float* ga = xp + (size_t)(p0 - 5 + row) * WDIM + (q0 - 8 + 4 * g);
        __builtin_amdgcn_global_load_lds(
            (const __attribute__((address_space(1))) uint32_t*)ga,
            (__attribute__((address_space(3))) uint32_t*)&lds[slot * 4],
            16, 0, 0);
      }
    }
  } else {
    // Diagonal / edge tile: reg roundtrip with causal + bounds masking.
#pragma unroll
    for (int j = 0; j < 6; ++j) {
      int slot = j * 256 + tid;
      if (slot < NSLOT) {
        int row = slot / NGRP;
        int gp = slot - row * NGRP;
        int g = gp ^ ((row >> 1) & 1);
        int ih = p0 - 5 + row;
        int cb = q0 - 8 + 4 * g;
        float4 v = make_float4(0.f, 0.f, 0.f, 0.f);
        if (ih >= 0) {  // ih < HDIM always (p0+31 <= 2047)
          if (cb >= 0 && cb + 3 <= ih && cb + 3 < WDIM) {
            v = *(const float4*)(xp + (size_t)ih * WDIM + cb);
          } else {
            float* vv = &v.x;
#pragma unroll
            for (int e = 0; e < 4; ++e) {
              int iw = cb + e;
              if (iw >= 0 && iw < WDIM && iw <= ih)
                vv[e] = xp[(size_t)ih * WDIM + iw];
            }
          }
        }
        *(float4*)&lds[slot * 4] = v;
      }
    }
  }

  __syncthreads();

  // ---- Compute: 2x8 register blocking per thread ----
  const int tx = tid & 15;        // 8 output cols each
  const int ty = tid >> 4;        // 2 output rows each
  const int orow0 = ty * 2;
  const int ocol0 = tx * 8;

  float acc[2][8];
#pragma unroll
  for (int a = 0; a < 2; ++a)
#pragma unroll
    for (int b = 0; b < 8; ++b) acc[a][b] = 0.f;

#pragma unroll
  for (int ihl = 0; ihl < 7; ++ihl) {  // 7 LDS rows feed 2 output rows
    const int l = orow0 + ihl;
    const int xr = (l >> 1) & 1;       // de-swizzle (wave rows step by 2)
    float xrow[24];                    // logical cols [ocol0, ocol0+24)
#pragma unroll
    for (int k = 0; k < 6; ++k) {
      int gs = (tx * 2 + k) ^ xr;
      *(float4*)&xrow[4 * k] = *(const float4*)&lds[(l * NGRP + gs) * 4];
    }
#pragma unroll
    for (int ro = 0; ro < 2; ++ro) {
      if (ro < ihl - 5 || ro > ihl) continue;  // compile-time after unroll
      const int rr = ihl - ro;                 // tap row 0..5
#pragma unroll
      for (int s = 0; s < STAP; ++s) {
        const float wv = wr[rr * STAP + s];
#pragma unroll
        for (int cc = 0; cc < 8; ++cc)
          acc[ro][cc] += wv * xrow[cc + s + 3];  // idx in [3,20]
      }
    }
  }

  // ---- Store with causal output mask ----
#pragma unroll
  for (int ro = 0; ro < 2; ++ro) {
    const int p = p0 + orow0 + ro;
    const int qb = q0 + ocol0;
#pragma unroll
    for (int cc = 0; cc < 8; ++cc)
      if (qb + cc > p) acc[ro][cc] = 0.f;
    *(float4*)(op + (size_t)p * WDIM + qb) =
        make_float4(acc[ro][0], acc[ro][1], acc[ro][2], acc[ro][3]);
    *(float4*)(op + (size_t)p * WDIM + qb + 4) =
        make_float4(acc[ro][4], acc[ro][5], acc[ro][6], acc[ro][7]);
  }
}

extern "C" void kernel_launch(void* const* d_in, const int* in_sizes, int n_in,
                              void* d_out, int out_size, void* d_ws, size_t ws_size,
                              hipStream_t stream) {
  const float* x   = (const float*)d_in[0];
  const float* wgt = (const float*)d_in[1];
  float* out       = (float*)d_out;
  dim3 grid(WDIM / TW, HDIM / TH, 2 * CH);  // (16, 64, 32)
  dwconv_causal<<<grid, dim3(256), 0, stream>>>(x, wgt, out);
}